// Round 7
// baseline (27.171 us; speedup 1.0000x reference)
//
#include <hip/hip_runtime.h>

// Bezier2Image: res[b,w,v] = min(1, sum_k gX[b,w,k]*gY[b,v,k])
// Barrier-free main loop: each wave owns a disjoint K-slice (curves) AND a
// private 8KB LDS slice, staging the truncated 8px gaussian windows DIRECTLY
// in mfma_f32_32x32x16_f16 fragment layout:
//   region r = mat*4 + rowhalf*2 + kstep (1KB each);
//   elem(mat,row,col) = r*512 + ((col>>3&1)*32 + (row&31))*8 + (col&7)
// so fragment reads are ds_read_b128 at base + lane*16 + r*1024 (linear,
// conflict-free, immediate offsets). Producer == consumer wave -> no
// __syncthreads in the main loop; same-wave DS ops are in-order at HW level.
// COMPILER ordering (R6 bug): the fragment-load addresses are loop-invariant,
// so without a fence LLVM LICM-hoists them above the scatter stores (vector
// f16x8 loads vs scalar _Float16 stores alias-analysis) -> all-zero output.
// Fix: asm volatile("" ::: "memory") fences around the scatter (zero insts).

namespace {
constexpr int   kN = 30;              // samples per curve
constexpr int   kW = 60;              // image side
constexpr int   kL = 160;             // curves per batch
constexpr int   kB = 128;             // batch
constexpr float kAlphaInv = 5000.0f;  // 1/2e-4
constexpr float kRadPix = 3.5f;       // truncation radius in pixels
constexpr int   kPix = kW * kW;       // 3600
}

using f32x16 = __attribute__((ext_vector_type(16))) float;
using f16x8  = __attribute__((ext_vector_type(8))) _Float16;

#define LDS_FENCE() asm volatile("" ::: "memory")

template <int KSPLIT>
__global__ __launch_bounds__(256, 2) void bezier_gemm_kernel(const float* __restrict__ x,
                                                             float* __restrict__ partial) {
  constexpr int CPB = kL / KSPLIT;    // curves per block
  constexpr int CPW = CPB / 4;        // curves (= steps) per wave
  __shared__ _Float16 sh[4 * 4096];   // 32 KB: 4 waves x 8KB private staging
  const int b    = blockIdx.x / KSPLIT;
  const int ks   = blockIdx.x % KSPLIT;
  const int tid  = threadIdx.x;
  const int lane = tid & 63;
  const int wid  = tid >> 6;
  const int l31  = lane & 31;

  _Float16* wsh = sh + wid * 4096;    // wave-private (4096 f16 = 8KB)

  // fixed staging role: mat = lane>>5 (0=gX,1=gY), col = sample n = lane&31
  const int mat = lane >> 5;
  const int col = l31;
  const bool valid = (col < kN);
  // constant part of the fragment-layout element index for this column
  const int colbase = (mat * 4 + (col >> 4)) * 512 + ((col >> 3) & 1) * 256 + (col & 7);

  float B0, B1, B2, B3;
  {
    float t0 = (float)col * (1.0f / 30.0f);
    float t  = 2.0f * t0 * t0 * t0 - 3.0f * t0 * t0 + 2.0f * t0;
    float t2 = t * t, t3 = t2 * t;
    B0 = t3;
    B1 = 3.0f * (t2 - t3);
    B2 = 3.0f * (t3 - 2.0f * t2 + t);
    float omt = 1.0f - t;
    B3 = omt * omt * omt;
  }

  // init-zero own wave slice (8KB): 8 x ds_write_b128 per lane, no barrier
  {
    uint4* z = (uint4*)wsh;
#pragma unroll
    for (int i = 0; i < 8; ++i) z[lane + i * 64] = make_uint4(0, 0, 0, 0);
  }
  LDS_FENCE();                        // init stores ordered before any loads

  f32x16 acc[2][2] = {};              // full 64x64 per wave
  const float* xb = x + ((size_t)b * kL + (size_t)ks * CPB + (size_t)wid * CPW) * 8;
  const _Float16* rbase = wsh + lane * 8;   // lane*16B

  int lo_prev = -100;                 // first step: nothing to zero
  for (int st = 0; st < CPW; ++st) {
    LDS_FENCE();                      // prev-iter loads ordered before stores (WAR)
    // ---- scatter own column of this step's curve (wave-private, no barrier)
    if (valid) {
      const float4* c = (const float4*)(xb + st * 8);
      float4 c0 = c[0], c1 = c[1];
      float P = mat ? (B0 * c0.y + B1 * c0.w + B2 * c1.y + B3 * c1.w)
                    : (B0 * c0.x + B1 * c0.z + B2 * c1.x + B3 * c1.z);
      float fp = P * 60.0f;
      int lo = (int)ceilf(fp - kRadPix);
#pragma unroll
      for (int i = 0; i < 8; ++i) {   // zero previous window
        int m = lo_prev + i;
        if (m >= 0 && m < kW)
          wsh[colbase + ((m >> 5) << 10) + ((m & 31) << 3)] = (_Float16)0.0f;
      }
#pragma unroll
      for (int i = 0; i < 8; ++i) {   // write new window
        int m = lo + i;
        if (m >= 0 && m < kW) {
          float d = (float)m * (1.0f / 60.0f) - P;
          wsh[colbase + ((m >> 5) << 10) + ((m & 31) << 3)] =
              (_Float16)__expf(-d * d * kAlphaInv);
        }
      }
      lo_prev = lo;
    }
    LDS_FENCE();                      // stores ordered before this iter's loads (RAW)

    // ---- fragment reads (conflict-free linear) + MFMA; k-step 0 then 1
    f16x8 a0k0 = *(const f16x8*)(rbase + 0 * 512);
    f16x8 a1k0 = *(const f16x8*)(rbase + 2 * 512);
    f16x8 b0k0 = *(const f16x8*)(rbase + 4 * 512);
    f16x8 b1k0 = *(const f16x8*)(rbase + 6 * 512);
    acc[0][0] = __builtin_amdgcn_mfma_f32_32x32x16_f16(a0k0, b0k0, acc[0][0], 0, 0, 0);
    acc[0][1] = __builtin_amdgcn_mfma_f32_32x32x16_f16(a0k0, b1k0, acc[0][1], 0, 0, 0);
    acc[1][0] = __builtin_amdgcn_mfma_f32_32x32x16_f16(a1k0, b0k0, acc[1][0], 0, 0, 0);
    acc[1][1] = __builtin_amdgcn_mfma_f32_32x32x16_f16(a1k0, b1k0, acc[1][1], 0, 0, 0);
    f16x8 a0k1 = *(const f16x8*)(rbase + 1 * 512);
    f16x8 a1k1 = *(const f16x8*)(rbase + 3 * 512);
    f16x8 b0k1 = *(const f16x8*)(rbase + 5 * 512);
    f16x8 b1k1 = *(const f16x8*)(rbase + 7 * 512);
    acc[0][0] = __builtin_amdgcn_mfma_f32_32x32x16_f16(a0k1, b0k1, acc[0][0], 0, 0, 0);
    acc[0][1] = __builtin_amdgcn_mfma_f32_32x32x16_f16(a0k1, b1k1, acc[0][1], 0, 0, 0);
    acc[1][0] = __builtin_amdgcn_mfma_f32_32x32x16_f16(a1k1, b0k1, acc[1][0], 0, 0, 0);
    acc[1][1] = __builtin_amdgcn_mfma_f32_32x32x16_f16(a1k1, b1k1, acc[1][1], 0, 0, 0);
  }

  // ---- epilogue: tree-reduce 4 wave accs in reused LDS (2 slots of 64x64 f32)
  __syncthreads();
  float* red = (float*)sh;
  const int hi2 = lane >> 5;
  if (wid < 2) {
    float* slot = red + wid * 4096;
#pragma unroll
    for (int mi = 0; mi < 2; ++mi)
#pragma unroll
      for (int vi = 0; vi < 2; ++vi)
#pragma unroll
        for (int r = 0; r < 16; ++r) {
          int row = mi * 32 + (r & 3) + 8 * (r >> 2) + 4 * hi2;
          slot[row * 64 + vi * 32 + l31] = acc[mi][vi][r];
        }
  }
  __syncthreads();
  if (wid >= 2) {
    float* slot = red + (wid - 2) * 4096;
#pragma unroll
    for (int mi = 0; mi < 2; ++mi)
#pragma unroll
      for (int vi = 0; vi < 2; ++vi)
#pragma unroll
        for (int r = 0; r < 16; ++r) {
          int row = mi * 32 + (r & 3) + 8 * (r >> 2) + 4 * hi2;
          slot[row * 64 + vi * 32 + l31] += acc[mi][vi][r];
        }
  }
  __syncthreads();

  float* pb = partial + (size_t)blockIdx.x * kPix;
  for (int p = tid; p < kPix; p += 256) {
    int r = p / kW;
    int c = p - r * kW;
    int idx = r * 64 + c;
    pb[p] = red[idx] + red[4096 + idx];
  }
}

template <int KSPLIT>
__global__ __launch_bounds__(256) void reduce_kernel(const float* __restrict__ partial,
                                                     float* __restrict__ out) {
  constexpr int F4 = kPix / 4;        // 900 float4 per image
  int i = blockIdx.x * 256 + threadIdx.x;
  if (i >= kB * F4) return;
  int b = i / F4;
  int j = i - b * F4;
  const float4* p = (const float4*)partial + (size_t)b * KSPLIT * F4 + j;
  float4 s = p[0];
#pragma unroll
  for (int k = 1; k < KSPLIT; ++k) {
    float4 t = p[(size_t)k * F4];
    s.x += t.x; s.y += t.y; s.z += t.z; s.w += t.w;
  }
  float4 r;
  r.x = fminf(s.x, 1.0f);
  r.y = fminf(s.y, 1.0f);
  r.z = fminf(s.z, 1.0f);
  r.w = fminf(s.w, 1.0f);
  ((float4*)out)[i] = r;
}

// Fallback if ws is too small: one block per batch, LDS-atomic splat, direct write.
__global__ __launch_bounds__(1024) void splat_direct_kernel(const float* __restrict__ x,
                                                            float* __restrict__ out) {
  __shared__ float res[kPix];
  const int b = blockIdx.x;
  const int tid = threadIdx.x;
  for (int i = tid; i < kPix; i += 1024) res[i] = 0.0f;
  __syncthreads();
  const float* xb = x + (size_t)b * kL * 8;
  for (int p = tid; p < kL * kN; p += 1024) {
    int l = p / kN;
    int n = p - l * kN;
    float t0 = (float)n * (1.0f / 30.0f);
    float t  = 2.0f * t0 * t0 * t0 - 3.0f * t0 * t0 + 2.0f * t0;
    float t2 = t * t, t3 = t2 * t;
    float B0 = t3, B1 = 3.0f * (t2 - t3), B2 = 3.0f * (t3 - 2.0f * t2 + t);
    float omt = 1.0f - t, B3 = omt * omt * omt;
    const float4* c = (const float4*)(xb + l * 8);
    float4 c0 = c[0], c1 = c[1];
    float X = B0 * c0.x + B1 * c0.z + B2 * c1.x + B3 * c1.z;
    float Y = B0 * c0.y + B1 * c0.w + B2 * c1.y + B3 * c1.w;
    float fx = X * kW, fy = Y * kW;
    int wlo = (int)ceilf(fx - kRadPix), vlo = (int)ceilf(fy - kRadPix);
    for (int i = 0; i < 8; ++i) {
      int w = wlo + i;
      if (w < 0 || w >= kW) continue;
      float dw = ((float)w - fx) * (1.0f / kW);
      float gx = __expf(-dw * dw * kAlphaInv);
      for (int j = 0; j < 8; ++j) {
        int v = vlo + j;
        if (v < 0 || v >= kW) continue;
        float dv = ((float)v - fy) * (1.0f / kW);
        atomicAdd(&res[w * kW + v], gx * __expf(-dv * dv * kAlphaInv));
      }
    }
  }
  __syncthreads();
  float* outb = out + (size_t)b * kPix;
  for (int i = tid; i < kPix; i += 1024) outb[i] = fminf(res[i], 1.0f);
}

extern "C" void kernel_launch(void* const* d_in, const int* in_sizes, int n_in,
                              void* d_out, int out_size, void* d_ws, size_t ws_size,
                              hipStream_t stream) {
  const float* x = (const float*)d_in[0];
  float* out = (float*)d_out;
  const size_t p8 = (size_t)kB * 8 * kPix * sizeof(float);   // 14.75 MB
  const size_t p4 = (size_t)kB * 4 * kPix * sizeof(float);   //  7.37 MB
  const int n4 = kB * kPix / 4;

  if (ws_size >= p8) {
    float* partial = (float*)d_ws;
    bezier_gemm_kernel<8><<<dim3(kB * 8), dim3(256), 0, stream>>>(x, partial);
    reduce_kernel<8><<<dim3((n4 + 255) / 256), dim3(256), 0, stream>>>(partial, out);
  } else if (ws_size >= p4) {
    float* partial = (float*)d_ws;
    bezier_gemm_kernel<4><<<dim3(kB * 4), dim3(256), 0, stream>>>(x, partial);
    reduce_kernel<4><<<dim3((n4 + 255) / 256), dim3(256), 0, stream>>>(partial, out);
  } else {
    splat_direct_kernel<<<dim3(kB), dim3(1024), 0, stream>>>(x, out);
  }
}